// Round 10
// baseline (313.351 us; speedup 1.0000x reference)
//
#include <hip/hip_runtime.h>
#include <hip/hip_bf16.h>

typedef __bf16 bf16x8 __attribute__((ext_vector_type(8)));
typedef float  f32x4  __attribute__((ext_vector_type(4)));
typedef float  float4v __attribute__((ext_vector_type(4)));
typedef short  short4v __attribute__((ext_vector_type(4)));

static constexpr int Tn  = 2048;
static constexpr int Bn  = 16;
static constexpr int Cn  = 768;
static constexpr int KT  = 12;       // 768 / 64 K-steps

#define MFMA16x16(a, b, c) __builtin_amdgcn_mfma_f32_16x16x32_bf16(a, b, c, 0, 0, 0)
#define DS_WAIT    asm volatile("s_waitcnt lgkmcnt(0)" ::: "memory")

__device__ __forceinline__ void gload_lds16(const void* g, void* l) {
  __builtin_amdgcn_global_load_lds((const __attribute__((address_space(1))) void*)g,
                                   (__attribute__((address_space(3))) void*)l, 16, 0, 0);
}

// ---------------- persistent attention colsum, 2-phase K-step (R9, measured 105 us):
__global__ __launch_bounds__(512, 2)
void attn_kernel(const __bf16* __restrict__ Z, const __bf16* __restrict__ X,
                 const float* __restrict__ u, const float* __restrict__ v,
                 float* __restrict__ wsum)
{
  __shared__ char lds[131072];
  const int i   = blockIdx.x;          // 256
  const int xcd = i & 7, j = i >> 3;   // j 0..31
  const int b    = xcd * 2 + (j >> 4);
  const int qt   = (j >> 1) & 7;
  const int half = j & 1;              // kt in {half*4 .. half*4+3}

  const int tid  = threadIdx.x;
  const int lane = tid & 63;
  const int w    = tid >> 6;
  const int wm   = w >> 2, wn = w & 3;
  const int lrow = lane & 15;
  const int lcb  = (lane >> 4) * 16;
  const int ar   = wm * 128 + lrow;
  const int br   = wn * 64 + lrow;
  const int crow = (lane >> 4) * 4;

  const int aB = ar * 64 + (lcb ^ (((ar >> 1) & 3) << 4));
  const int bB = br * 64 + (lcb ^ (((br >> 1) & 3) << 4));

  const int    l0 = tid * 16,            l1 = tid * 16 + 8192;
  const size_t g0 = (size_t)(l0 >> 6) * 1536 + ((l0 & 63) ^ (((l0 >> 7) & 3) << 4));
  const size_t g1 = (size_t)(l1 >> 6) * 1536 + ((l1 & 63) ^ (((l1 >> 7) & 3) << 4));

  const char* Ab  = (const char*)(Z + ((size_t)b * Tn + qt * 256) * Cn);
  const char* Xb0 = (const char*)(X + ((size_t)b * Tn + (size_t)(half * 4) * 256) * Cn);

#define STAGE(gk, du) do { const char* _g = (gk); char* _d = (du); \
    gload_lds16(_g + g0, _d + l0); gload_lds16(_g + g1, _d + l1); } while (0)

  STAGE(Ab,       lds + 0);
  STAGE(Xb0,      lds + 32768);
  STAGE(Ab + 64,  lds + 16384);
  STAGE(Xb0 + 64, lds + 49152);
  asm volatile("s_waitcnt vmcnt(0)" ::: "memory");
  __builtin_amdgcn_s_barrier();

  const float kf = 0.036084391824351615f * 1.4426950408889634f;  // scale * log2(e)
  int cur = 0;

#pragma unroll 1
  for (int tt = 0; tt < 4; ++tt) {
    const int kt = half * 4 + tt;
    f32x4 acc[8][4] = {};

    for (int t = 0; t < KT; ++t) {
      const char* bp = lds + cur * 65536;
      char*       bq = lds + (cur ^ 1) * 65536;
      const bool last = (t == KT - 1);
      const bool st   = !(tt == 3 && last);
      const size_t koff = last ? 0 : (size_t)(t + 1) * 128;
      const char* gA = Ab + koff;
      const char* gB = Xb0 + (size_t)(tt + (last ? 1 : 0)) * 393216 + koff;
      bf16x8 aF[8], bF[4];

      // ---- phase ks0
#pragma unroll
      for (int i2 = 0; i2 < 4; ++i2) bF[i2] = *(const bf16x8*)(bp + 32768 + bB + i2 * 1024);
#pragma unroll
      for (int i2 = 0; i2 < 4; ++i2) aF[i2]     = *(const bf16x8*)(bp + aB + i2 * 1024);
#pragma unroll
      for (int i2 = 0; i2 < 4; ++i2) aF[4 + i2] = *(const bf16x8*)(bp + aB + 4096 + i2 * 1024);
      if (st) { STAGE(gA, bq); STAGE(gB, bq + 32768); }
      DS_WAIT;
      __builtin_amdgcn_s_setprio(1);
#pragma unroll
      for (int i2 = 0; i2 < 8; ++i2)
#pragma unroll
        for (int j2 = 0; j2 < 4; ++j2)
          acc[i2][j2] = MFMA16x16(aF[i2], bF[j2], acc[i2][j2]);
      __builtin_amdgcn_s_setprio(0);
      if (st) { asm volatile("s_waitcnt vmcnt(4)" ::: "memory"); }
      else    { asm volatile("s_waitcnt vmcnt(0)" ::: "memory"); }
      __builtin_amdgcn_s_barrier();

      // ---- phase ks1
#pragma unroll
      for (int i2 = 0; i2 < 4; ++i2) bF[i2] = *(const bf16x8*)(bp + 49152 + bB + i2 * 1024);
#pragma unroll
      for (int i2 = 0; i2 < 4; ++i2) aF[i2]     = *(const bf16x8*)(bp + 16384 + aB + i2 * 1024);
#pragma unroll
      for (int i2 = 0; i2 < 4; ++i2) aF[4 + i2] = *(const bf16x8*)(bp + 16384 + aB + 4096 + i2 * 1024);
      if (st) { STAGE(gA + 64, bq + 16384); STAGE(gB + 64, bq + 49152); }
      DS_WAIT;
      __builtin_amdgcn_s_setprio(1);
#pragma unroll
      for (int i2 = 0; i2 < 8; ++i2)
#pragma unroll
        for (int j2 = 0; j2 < 4; ++j2)
          acc[i2][j2] = MFMA16x16(aF[i2], bF[j2], acc[i2][j2]);
      __builtin_amdgcn_s_setprio(0);
      if (st) { asm volatile("s_waitcnt vmcnt(4)" ::: "memory"); }
      else    { asm volatile("s_waitcnt vmcnt(0)" ::: "memory"); }
      __builtin_amdgcn_s_barrier();
      cur ^= 1;
    }

    // per-tile epilogue: sigmoid + column-sum + atomics (no LDS use)
    float vv[4];
#pragma unroll
    for (int ni = 0; ni < 4; ++ni)
      vv[ni] = v[(size_t)b * Tn + kt * 256 + wn * 64 + ni * 16 + lrow];

    float csum[4] = {0.f, 0.f, 0.f, 0.f};
#pragma unroll
    for (int mi = 0; mi < 8; ++mi) {
      const f32x4 uu = *(const f32x4*)&u[(size_t)b * Tn + qt * 256 + wm * 128 +
                                         (mi >> 2) * 64 + (mi & 3) * 16 + crow];
#pragma unroll
      for (int ni = 0; ni < 4; ++ni)
#pragma unroll
        for (int rr = 0; rr < 4; ++rr) {
          const float e = __builtin_amdgcn_exp2f(-(acc[mi][ni][rr] + uu[rr] + vv[ni]) * kf);
          csum[ni] += __builtin_amdgcn_rcpf(1.f + e);
        }
    }
#pragma unroll
    for (int ni = 0; ni < 4; ++ni) {
      csum[ni] += __shfl_xor(csum[ni], 16);
      csum[ni] += __shfl_xor(csum[ni], 32);
    }
    if (lane < 16) {
#pragma unroll
      for (int ni = 0; ni < 4; ++ni)
        atomicAdd(&wsum[(size_t)b * Tn + kt * 256 + wn * 64 + ni * 16 + lane], csum[ni]);
    }
  }
#undef STAGE
}

// ---------------- Z = X * Gt^T: 256x384 tiles, 256 blocks, one round.
// 2-barrier K-step (mirror of attn's R9 transformation, VGPR-neutral: aF[4] reloaded
// between the two MFMA clusters of each ks-half; no barrier needed between clusters
// since all reads hit bp and all staging writes bq).
__global__ __launch_bounds__(512, 2)
void z_kernel(const __bf16* __restrict__ X, const __bf16* __restrict__ Gt,
              __hip_bfloat16* __restrict__ Zo)
{
  __shared__ char lds[163840];   // 2 x (A 2x16KB + B 2x24KB) = 2 x 80KB
  int f = blockIdx.x;            // 256
  f = (f & 7) * 32 + (f >> 3);   // XCD-chunked
  const int tn = f & 1, tm = f >> 1;
  const int tile_m = tm * 256, tile_n = tn * 384;

  const int tid  = threadIdx.x;
  const int lane = tid & 63;
  const int w    = tid >> 6;
  const int wm   = w >> 2, wn = w & 3;   // wave tile 128x96
  const int lrow = lane & 15;
  const int lcb  = (lane >> 4) * 16;
  const int ar   = wm * 128 + lrow;
  const int br   = wn * 96 + lrow;
  const int aB = ar * 64 + (lcb ^ (((ar >> 1) & 3) << 4));
  const int bB = br * 64 + (lcb ^ (((br >> 1) & 3) << 4));

  const int    l0 = tid * 16, l1 = l0 + 8192, l2 = l0 + 16384;
  const size_t g0 = (size_t)(l0 >> 6) * 1536 + ((l0 & 63) ^ (((l0 >> 7) & 3) << 4));
  const size_t g1 = (size_t)(l1 >> 6) * 1536 + ((l1 & 63) ^ (((l1 >> 7) & 3) << 4));
  const size_t g2 = (size_t)(l2 >> 6) * 1536 + ((l2 & 63) ^ (((l2 >> 7) & 3) << 4));

  const char* Ab = (const char*)(X + (size_t)tile_m * Cn);
  const char* Bb = (const char*)(Gt + (size_t)tile_n * Cn);

#define STAGEA(gk, du) do { const char* _g = (gk); char* _d = (du); \
    gload_lds16(_g + g0, _d + l0); gload_lds16(_g + g1, _d + l1); } while (0)
#define STAGEB(gk, du) do { const char* _g = (gk); char* _d = (du); \
    gload_lds16(_g + g0, _d + l0); gload_lds16(_g + g1, _d + l1); \
    gload_lds16(_g + g2, _d + l2); } while (0)

  f32x4 acc[8][6] = {};

  STAGEA(Ab,      lds + 0);
  STAGEB(Bb,      lds + 32768);
  STAGEA(Ab + 64, lds + 16384);
  STAGEB(Bb + 64, lds + 57344);
  asm volatile("s_waitcnt vmcnt(0)" ::: "memory");
  __builtin_amdgcn_s_barrier();

  for (int t = 0; t < KT; ++t) {
    const char* bp = lds + (t & 1) * 81920;
    char*       bq = lds + ((t + 1) & 1) * 81920;
    const char* gA = Ab + (size_t)(t + 1) * 128;
    const char* gB = Bb + (size_t)(t + 1) * 128;
    const bool st  = (t < KT - 1);
    bf16x8 aF[4], bF[6];

    // ---- merged phase ks0
#pragma unroll
    for (int i2 = 0; i2 < 6; ++i2) bF[i2] = *(const bf16x8*)(bp + 32768 + bB + i2 * 1024);
#pragma unroll
    for (int i2 = 0; i2 < 4; ++i2) aF[i2] = *(const bf16x8*)(bp + aB + i2 * 1024);
    if (st) STAGEA(gA, bq);
    DS_WAIT;
    __builtin_amdgcn_s_setprio(1);
#pragma unroll
    for (int i2 = 0; i2 < 4; ++i2)
#pragma unroll
      for (int j2 = 0; j2 < 6; ++j2)
        acc[i2][j2] = MFMA16x16(aF[i2], bF[j2], acc[i2][j2]);
    __builtin_amdgcn_s_setprio(0);
#pragma unroll
    for (int i2 = 0; i2 < 4; ++i2) aF[i2] = *(const bf16x8*)(bp + aB + 4096 + i2 * 1024);
    if (st) STAGEB(gB, bq + 32768);
    DS_WAIT;
    __builtin_amdgcn_s_setprio(1);
#pragma unroll
    for (int i2 = 0; i2 < 4; ++i2)
#pragma unroll
      for (int j2 = 0; j2 < 6; ++j2)
        acc[4 + i2][j2] = MFMA16x16(aF[i2], bF[j2], acc[4 + i2][j2]);
    __builtin_amdgcn_s_setprio(0);
    if (st) { asm volatile("s_waitcnt vmcnt(5)" ::: "memory"); }
    else    { asm volatile("s_waitcnt vmcnt(0)" ::: "memory"); }
    __builtin_amdgcn_s_barrier();

    // ---- merged phase ks1
#pragma unroll
    for (int i2 = 0; i2 < 6; ++i2) bF[i2] = *(const bf16x8*)(bp + 57344 + bB + i2 * 1024);
#pragma unroll
    for (int i2 = 0; i2 < 4; ++i2) aF[i2] = *(const bf16x8*)(bp + 16384 + aB + i2 * 1024);
    if (st) STAGEA(gA + 64, bq + 16384);
    DS_WAIT;
    __builtin_amdgcn_s_setprio(1);
#pragma unroll
    for (int i2 = 0; i2 < 4; ++i2)
#pragma unroll
      for (int j2 = 0; j2 < 6; ++j2)
        acc[i2][j2] = MFMA16x16(aF[i2], bF[j2], acc[i2][j2]);
    __builtin_amdgcn_s_setprio(0);
#pragma unroll
    for (int i2 = 0; i2 < 4; ++i2) aF[i2] = *(const bf16x8*)(bp + 16384 + aB + 4096 + i2 * 1024);
    if (st) STAGEB(gB + 64, bq + 57344);
    DS_WAIT;
    __builtin_amdgcn_s_setprio(1);
#pragma unroll
    for (int i2 = 0; i2 < 4; ++i2)
#pragma unroll
      for (int j2 = 0; j2 < 6; ++j2)
        acc[4 + i2][j2] = MFMA16x16(aF[i2], bF[j2], acc[4 + i2][j2]);
    __builtin_amdgcn_s_setprio(0);
    if (st) { asm volatile("s_waitcnt vmcnt(5)" ::: "memory"); }
    else    { asm volatile("s_waitcnt vmcnt(0)" ::: "memory"); }
    __builtin_amdgcn_s_barrier();
  }
#undef STAGEA
#undef STAGEB

  // epilogue: banded LDS repack [64][392 bf16] -> coalesced stores
  __bf16* cb = (__bf16*)lds;
  const int crow = (lane >> 4) * 4;
  for (int rb = 0; rb < 4; ++rb) {
    __syncthreads();
    if (wm == (rb >> 1)) {
#pragma unroll
      for (int mi2 = 0; mi2 < 4; ++mi2) {
        const int mi = (rb & 1) * 4 + mi2;
        const int lr = mi2 * 16 + crow;
#pragma unroll
        for (int ni = 0; ni < 6; ++ni) {
          const int col = wn * 96 + ni * 16 + lrow;
#pragma unroll
          for (int r = 0; r < 4; ++r)
            cb[(lr + r) * 392 + col] = (__bf16)acc[mi][ni][r];
        }
      }
    }
    __syncthreads();
    const int row = tid >> 3;
    const int seg = tid & 7;
    char* gout = (char*)Zo + (size_t)(tile_m + rb * 64 + row) * 1536 + tile_n * 2 + seg * 96;
    const char* lsrc = (const char*)cb + row * 784 + seg * 96;
#pragma unroll
    for (int i2 = 0; i2 < 6; ++i2)
      *(float4v*)(gout + i2 * 16) = *(const float4v*)(lsrc + i2 * 16);
  }
}

// ---------------- Gt[c'][c] = sum_d Wk[d,c']*Wq[d,c], fp32 in (transpose via LDS), bf16 out
__global__ __launch_bounds__(256)
void gt_kernel(const float* __restrict__ Wk, const float* __restrict__ Wq,
               __bf16* __restrict__ Gt)
{
  __shared__ __bf16 ak[64 * 40], bkl[64 * 40];   // [col][d], stride 40 (80B, 16B-aligned)
  const int t  = threadIdx.x;
  const int tm = (blockIdx.x / 12) * 64;   // c' tile
  const int tn = (blockIdx.x % 12) * 64;   // c  tile
  const int lane = t & 63, w = t >> 6;
  const int wm = w >> 1, wn = w & 1;       // 2x2 waves of 32x32
  const int lrow = lane & 15, lk8 = (lane >> 4) * 8, crow = (lane >> 4) * 4;
  const int lc = t & 63, ld = t >> 6;
  f32x4 acc[2][2] = {};

  for (int d0 = 0; d0 < 768; d0 += 32) {
    __syncthreads();
#pragma unroll
    for (int dd = 0; dd < 8; ++dd) {
      const int dl = ld + dd * 4;
      ak [lc * 40 + dl] = (__bf16)Wk[(size_t)(d0 + dl) * 768 + tm + lc];
      bkl[lc * 40 + dl] = (__bf16)Wq[(size_t)(d0 + dl) * 768 + tn + lc];
    }
    __syncthreads();
    bf16x8 a[2], b2[2];
#pragma unroll
    for (int mi = 0; mi < 2; ++mi)
      a[mi] = *(const bf16x8*)&ak[(wm * 32 + mi * 16 + lrow) * 40 + lk8];
#pragma unroll
    for (int ni = 0; ni < 2; ++ni)
      b2[ni] = *(const bf16x8*)&bkl[(wn * 32 + ni * 16 + lrow) * 40 + lk8];
#pragma unroll
    for (int mi = 0; mi < 2; ++mi)
#pragma unroll
      for (int ni = 0; ni < 2; ++ni)
        acc[mi][ni] = MFMA16x16(a[mi], b2[ni], acc[mi][ni]);
  }
#pragma unroll
  for (int mi = 0; mi < 2; ++mi)
#pragma unroll
    for (int ni = 0; ni < 2; ++ni)
#pragma unroll
      for (int r = 0; r < 4; ++r)
        Gt[(size_t)(tm + wm * 32 + mi * 16 + crow + r) * 768 +
           tn + wn * 32 + ni * 16 + lrow] = (__bf16)acc[mi][ni][r];
}

// ---------------- wqbk[c] = sum_d Wq[d,c]*bk[d]; wkbq[c] = sum_d Wk[d,c]*bq[d]; c0 = bq.bk
__global__ __launch_bounds__(256)
void biasprep(const float* __restrict__ Wq, const float* __restrict__ Wk,
              const float* __restrict__ bq, const float* __restrict__ bk,
              float* __restrict__ wqbk, float* __restrict__ wkbq, float* __restrict__ c0p)
{
  const int t = threadIdx.x, bx = blockIdx.x, by = blockIdx.y;
  if (by == 32) {
    if (bx == 0) {
      float s = 0.f;
#pragma unroll
      for (int i2 = 0; i2 < 3; ++i2) { const int d = t + i2 * 256; s += bq[d] * bk[d]; }
#pragma unroll
      for (int off = 32; off; off >>= 1) s += __shfl_down(s, off);
      __shared__ float rr[4];
      if ((t & 63) == 0) rr[t >> 6] = s;
      __syncthreads();
      if (t == 0) atomicAdd(c0p, rr[0] + rr[1] + rr[2] + rr[3]);
    }
    return;
  }
  const int c = bx * 256 + t;
  float aq = 0.f, ak2 = 0.f;
  for (int dd = 0; dd < 24; ++dd) {
    const int d = by * 24 + dd;
    aq  += Wq[(size_t)d * 768 + c] * bk[d];
    ak2 += Wk[(size_t)d * 768 + c] * bq[d];
  }
  atomicAdd(&wqbk[c], aq);
  atomicAdd(&wkbq[c], ak2);
}

// ---------------- cvt x->bf16 fused with u = x.wqbk + c0, v = x.wkbq
__global__ __launch_bounds__(512)
void cvt_x_uv(const float* __restrict__ x, const float* __restrict__ wqbk,
              const float* __restrict__ wkbq, const float* __restrict__ c0p,
              __hip_bfloat16* __restrict__ xb, float* __restrict__ u, float* __restrict__ v)
{
  __shared__ float wq_l[768], wk_l[768];
  const int t = threadIdx.x;
  for (int i = t; i < 768; i += 512) { wq_l[i] = wqbk[i]; wk_l[i] = wkbq[i]; }
  __syncthreads();
  const int lane = t & 63, wv = t >> 6;
  const int row = blockIdx.x * 8 + wv;
  const float4v* xr = (const float4v*)(x + (size_t)row * 768);
  short4v* xo = (short4v*)((__bf16*)xb + (size_t)row * 768);
  float du = 0.f, dv = 0.f;
#pragma unroll
  for (int i = 0; i < 3; ++i) {
    const int ch = lane + 64 * i;
    const float4v xv = xr[ch];
    short4v s;
#pragma unroll
    for (int j = 0; j < 4; ++j) {
      s[j] = __builtin_bit_cast(short, __float2bfloat16(xv[j]));
      du += xv[j] * wq_l[ch * 4 + j];
      dv += xv[j] * wk_l[ch * 4 + j];
    }
    xo[ch] = s;
  }
#pragma unroll
  for (int off = 1; off < 64; off <<= 1) {
    du += __shfl_xor(du, off);
    dv += __shfl_xor(dv, off);
  }
  if (lane == 0) { u[row] = du + *c0p; v[row] = dv; }
}

// ---------------- y[b,c] = sum_k w[b,k]*xb[b,k,c]; sw[b] = sum_k w[b,k]
// grid (16,64): 32 k-rows per block -> ~4 blocks/CU for latency hiding
__global__ __launch_bounds__(192)
void wx_kernel(const float* __restrict__ wsum, const __bf16* __restrict__ xb,
               float* __restrict__ y, float* __restrict__ swp)
{
  const int b = blockIdx.x, kc = blockIdx.y;
  const int t = threadIdx.x;
  const int chunk = t % 96, rg = t / 96;
  const __bf16* xr = xb + ((size_t)b * Tn + (size_t)kc * 32) * 768;
  const float*  wr = wsum + (size_t)b * Tn + (size_t)kc * 32;
  float acc[8] = {};
  float swl = 0.f;
  for (int k2 = 0; k2 < 16; ++k2) {
    const int k = k2 * 2 + rg;
    const float wk = wr[k];
    const bf16x8 v8 = *(const bf16x8*)&xr[(size_t)k * 768 + chunk * 8];
    if (chunk == 0) swl += wk;
#pragma unroll
    for (int j = 0; j < 8; ++j) acc[j] += wk * (float)v8[j];
  }
  float* yb = y + (size_t)b * 768 + chunk * 8;
#pragma unroll
  for (int j = 0; j < 8; ++j) atomicAdd(yb + j, acc[j]);
  if (chunk == 0) atomicAdd(&swp[b], swl);
}

// ---------------- out_pre[b,d] = ( y[b,:].Wv[d,:] + sw[b]*bv[d] ) / T
__global__ __launch_bounds__(256)
void vproj_kernel(const float* __restrict__ y, const float* __restrict__ swp,
                  const float* __restrict__ Wv, const float* __restrict__ bv,
                  float* __restrict__ opre)
{
  __shared__ float ys[768];
  const int b = blockIdx.x, dg = blockIdx.y, t = threadIdx.x;
  for (int i = t; i < 768; i += 256) ys[i] = y[(size_t)b * 768 + i];
  __syncthreads();
  const float sw = swp[b];
  const int d = dg * 256 + t;
  const float4v* wrow = (const float4v*)(Wv + (size_t)d * 768);
  const float4v* ysv  = (const float4v*)ys;
  float4v a = {};
  for (int c = 0; c < 192; ++c) {
    const float4v wv4 = wrow[c];
    const float4v yv4 = ysv[c];
#pragma unroll
    for (int j = 0; j < 4; ++j) a[j] += wv4[j] * yv4[j];
  }
  const float dot = a[0] + a[1] + a[2] + a[3];
  opre[(size_t)b * 768 + d] = (dot + sw * bv[d]) * (1.f / 2048.f);
}

// ---------------- BatchNorm1d over batch dim
__global__ void bn_kernel(const float* __restrict__ out_pre,
                          const float* __restrict__ gamma, const float* __restrict__ beta,
                          float* __restrict__ out)
{
  const int d = blockIdx.x * 256 + threadIdx.x;
  float vals[16];
  float s = 0.f;
#pragma unroll
  for (int b = 0; b < 16; ++b) { vals[b] = out_pre[b * Cn + d]; s += vals[b]; }
  const float mu = s * (1.f / 16.f);
  float s2 = 0.f;
#pragma unroll
  for (int b = 0; b < 16; ++b) { float t2 = vals[b] - mu; s2 += t2 * t2; }
  const float inv = rsqrtf(s2 * (1.f / 16.f) + 1e-5f);
  const float g = gamma[d] * inv, be = beta[d];
#pragma unroll
  for (int b = 0; b < 16; ++b) out[b * Cn + d] = (vals[b] - mu) * g + be;
}

extern "C" void kernel_launch(void* const* d_in, const int* in_sizes, int n_in,
                              void* d_out, int out_size, void* d_ws, size_t ws_size,
                              hipStream_t stream)
{
  const float* x  = (const float*)d_in[0];
  const float* Wq = (const float*)d_in[1];
  const float* bq = (const float*)d_in[2];
  const float* Wk = (const float*)d_in[3];
  const float* bk = (const float*)d_in[4];
  const float* Wv = (const float*)d_in[5];
  const float* bv = (const float*)d_in[6];
  const float* gamma = (const float*)d_in[7];
  const float* beta  = (const float*)d_in[8];
  float* out = (float*)d_out;

  char* ws = (char*)d_ws;
  // workspace layout (~97.6 MiB)
  __hip_bfloat16* xb  = (__hip_bfloat16*)(ws);                  // 50,331,648
  __hip_bfloat16* Zb  = (__hip_bfloat16*)(ws + 50331648);       // 50,331,648
  __bf16*         Gt  = (__bf16*)        (ws + 100663296);      //  1,179,648
  float*          u   = (float*)         (ws + 101842944);      //    131,072
  float*          v   = (float*)         (ws + 101974016);      //    131,072
  float*          wsum= (float*)         (ws + 102105088);      //    131,072  <- zero from here
  float*          yv  = (float*)         (ws + 102236160);      //     49,152
  float*          wqbk= (float*)         (ws + 102285312);      //      3,072
  float*          wkbq= (float*)         (ws + 102288384);      //      3,072
  float*          c0p = (float*)         (ws + 102291456);      //         64
  float*          swp = (float*)         (ws + 102291520);      //         64
  float*          opre= (float*)         (ws + 102291584);      //     49,152

  (void)in_sizes; (void)n_in; (void)out_size; (void)ws_size;

  // zero wsum + yv + wqbk + wkbq + c0 + sw (contiguous; atomics accumulate into these)
  hipMemsetAsync(wsum, 0, 131072 + 49152 + 3072 + 3072 + 64 + 64, stream);

  biasprep<<<dim3(3, 33), 256, 0, stream>>>(Wq, Wk, bq, bk, wqbk, wkbq, c0p);
  gt_kernel<<<dim3(144), 256, 0, stream>>>(Wk, Wq, Gt);
  cvt_x_uv<<<dim3(4096), 512, 0, stream>>>(x, wqbk, wkbq, c0p, xb, u, v);

  z_kernel<<<dim3(256), 512, 0, stream>>>((const __bf16*)xb, Gt, Zb);

  attn_kernel<<<dim3(256), 512, 0, stream>>>(
      (const __bf16*)Zb, (const __bf16*)xb, u, v, wsum);

  wx_kernel<<<dim3(16, 64), 192, 0, stream>>>(wsum, (const __bf16*)xb, yv, swp);
  vproj_kernel<<<dim3(16, 3), 256, 0, stream>>>(yv, swp, Wv, bv, opre);
  bn_kernel<<<dim3(3), 256, 0, stream>>>(opre, gamma, beta, out);
}

// Round 11
// 295.819 us; speedup vs baseline: 1.0593x; 1.0593x over previous
//
#include <hip/hip_runtime.h>
#include <hip/hip_bf16.h>

typedef __bf16 bf16x8 __attribute__((ext_vector_type(8)));
typedef float  f32x4  __attribute__((ext_vector_type(4)));
typedef float  float4v __attribute__((ext_vector_type(4)));
typedef short  short4v __attribute__((ext_vector_type(4)));

static constexpr int Tn  = 2048;
static constexpr int Bn  = 16;
static constexpr int Cn  = 768;
static constexpr int KT  = 12;       // 768 / 64 K-steps

#define MFMA16x16(a, b, c) __builtin_amdgcn_mfma_f32_16x16x32_bf16(a, b, c, 0, 0, 0)
#define DS_WAIT    asm volatile("s_waitcnt lgkmcnt(0)" ::: "memory")
#define DS_WAIT_SB do { asm volatile("s_waitcnt lgkmcnt(0)" ::: "memory"); \
                        __builtin_amdgcn_sched_barrier(0); } while (0)

__device__ __forceinline__ void gload_lds16(const void* g, void* l) {
  __builtin_amdgcn_global_load_lds((const __attribute__((address_space(1))) void*)g,
                                   (__attribute__((address_space(3))) void*)l, 16, 0, 0);
}

// ---------------- persistent attention colsum, 2-phase K-step (R9, measured 105 us):
__global__ __launch_bounds__(512, 2)
void attn_kernel(const __bf16* __restrict__ Z, const __bf16* __restrict__ X,
                 const float* __restrict__ u, const float* __restrict__ v,
                 float* __restrict__ wsum)
{
  __shared__ char lds[131072];
  const int i   = blockIdx.x;          // 256
  const int xcd = i & 7, j = i >> 3;   // j 0..31
  const int b    = xcd * 2 + (j >> 4);
  const int qt   = (j >> 1) & 7;
  const int half = j & 1;              // kt in {half*4 .. half*4+3}

  const int tid  = threadIdx.x;
  const int lane = tid & 63;
  const int w    = tid >> 6;
  const int wm   = w >> 2, wn = w & 3;
  const int lrow = lane & 15;
  const int lcb  = (lane >> 4) * 16;
  const int ar   = wm * 128 + lrow;
  const int br   = wn * 64 + lrow;
  const int crow = (lane >> 4) * 4;

  const int aB = ar * 64 + (lcb ^ (((ar >> 1) & 3) << 4));
  const int bB = br * 64 + (lcb ^ (((br >> 1) & 3) << 4));

  const int    l0 = tid * 16,            l1 = tid * 16 + 8192;
  const size_t g0 = (size_t)(l0 >> 6) * 1536 + ((l0 & 63) ^ (((l0 >> 7) & 3) << 4));
  const size_t g1 = (size_t)(l1 >> 6) * 1536 + ((l1 & 63) ^ (((l1 >> 7) & 3) << 4));

  const char* Ab  = (const char*)(Z + ((size_t)b * Tn + qt * 256) * Cn);
  const char* Xb0 = (const char*)(X + ((size_t)b * Tn + (size_t)(half * 4) * 256) * Cn);

#define STAGE(gk, du) do { const char* _g = (gk); char* _d = (du); \
    gload_lds16(_g + g0, _d + l0); gload_lds16(_g + g1, _d + l1); } while (0)

  STAGE(Ab,       lds + 0);
  STAGE(Xb0,      lds + 32768);
  STAGE(Ab + 64,  lds + 16384);
  STAGE(Xb0 + 64, lds + 49152);
  asm volatile("s_waitcnt vmcnt(0)" ::: "memory");
  __builtin_amdgcn_s_barrier();

  const float kf = 0.036084391824351615f * 1.4426950408889634f;  // scale * log2(e)
  int cur = 0;

#pragma unroll 1
  for (int tt = 0; tt < 4; ++tt) {
    const int kt = half * 4 + tt;
    f32x4 acc[8][4] = {};

    for (int t = 0; t < KT; ++t) {
      const char* bp = lds + cur * 65536;
      char*       bq = lds + (cur ^ 1) * 65536;
      const bool last = (t == KT - 1);
      const bool st   = !(tt == 3 && last);
      const size_t koff = last ? 0 : (size_t)(t + 1) * 128;
      const char* gA = Ab + koff;
      const char* gB = Xb0 + (size_t)(tt + (last ? 1 : 0)) * 393216 + koff;
      bf16x8 aF[8], bF[4];

      // ---- phase ks0
#pragma unroll
      for (int i2 = 0; i2 < 4; ++i2) bF[i2] = *(const bf16x8*)(bp + 32768 + bB + i2 * 1024);
#pragma unroll
      for (int i2 = 0; i2 < 4; ++i2) aF[i2]     = *(const bf16x8*)(bp + aB + i2 * 1024);
#pragma unroll
      for (int i2 = 0; i2 < 4; ++i2) aF[4 + i2] = *(const bf16x8*)(bp + aB + 4096 + i2 * 1024);
      if (st) { STAGE(gA, bq); STAGE(gB, bq + 32768); }
      DS_WAIT;
      __builtin_amdgcn_s_setprio(1);
#pragma unroll
      for (int i2 = 0; i2 < 8; ++i2)
#pragma unroll
        for (int j2 = 0; j2 < 4; ++j2)
          acc[i2][j2] = MFMA16x16(aF[i2], bF[j2], acc[i2][j2]);
      __builtin_amdgcn_s_setprio(0);
      if (st) { asm volatile("s_waitcnt vmcnt(4)" ::: "memory"); }
      else    { asm volatile("s_waitcnt vmcnt(0)" ::: "memory"); }
      __builtin_amdgcn_s_barrier();

      // ---- phase ks1
#pragma unroll
      for (int i2 = 0; i2 < 4; ++i2) bF[i2] = *(const bf16x8*)(bp + 49152 + bB + i2 * 1024);
#pragma unroll
      for (int i2 = 0; i2 < 4; ++i2) aF[i2]     = *(const bf16x8*)(bp + 16384 + aB + i2 * 1024);
#pragma unroll
      for (int i2 = 0; i2 < 4; ++i2) aF[4 + i2] = *(const bf16x8*)(bp + 16384 + aB + 4096 + i2 * 1024);
      if (st) { STAGE(gA + 64, bq + 16384); STAGE(gB + 64, bq + 49152); }
      DS_WAIT;
      __builtin_amdgcn_s_setprio(1);
#pragma unroll
      for (int i2 = 0; i2 < 8; ++i2)
#pragma unroll
        for (int j2 = 0; j2 < 4; ++j2)
          acc[i2][j2] = MFMA16x16(aF[i2], bF[j2], acc[i2][j2]);
      __builtin_amdgcn_s_setprio(0);
      if (st) { asm volatile("s_waitcnt vmcnt(4)" ::: "memory"); }
      else    { asm volatile("s_waitcnt vmcnt(0)" ::: "memory"); }
      __builtin_amdgcn_s_barrier();
      cur ^= 1;
    }

    // per-tile epilogue: sigmoid + column-sum + atomics (no LDS use)
    float vv[4];
#pragma unroll
    for (int ni = 0; ni < 4; ++ni)
      vv[ni] = v[(size_t)b * Tn + kt * 256 + wn * 64 + ni * 16 + lrow];

    float csum[4] = {0.f, 0.f, 0.f, 0.f};
#pragma unroll
    for (int mi = 0; mi < 8; ++mi) {
      const f32x4 uu = *(const f32x4*)&u[(size_t)b * Tn + qt * 256 + wm * 128 +
                                         (mi >> 2) * 64 + (mi & 3) * 16 + crow];
#pragma unroll
      for (int ni = 0; ni < 4; ++ni)
#pragma unroll
        for (int rr = 0; rr < 4; ++rr) {
          const float e = __builtin_amdgcn_exp2f(-(acc[mi][ni][rr] + uu[rr] + vv[ni]) * kf);
          csum[ni] += __builtin_amdgcn_rcpf(1.f + e);
        }
    }
#pragma unroll
    for (int ni = 0; ni < 4; ++ni) {
      csum[ni] += __shfl_xor(csum[ni], 16);
      csum[ni] += __shfl_xor(csum[ni], 32);
    }
    if (lane < 16) {
#pragma unroll
      for (int ni = 0; ni < 4; ++ni)
        atomicAdd(&wsum[(size_t)b * Tn + kt * 256 + wn * 64 + ni * 16 + lane], csum[ni]);
    }
  }
#undef STAGE
}

// ---------------- Z = X * Gt^T: 256x384 tiles, 256 blocks, one round
// (EXACT R8/R9 measured form: 4-phase, hoisted STAGEA/STAGEB, sched_barrier'd DS_WAIT.
//  DO NOT merge phases or drop the sched_barrier: acc[8][6]=192 VGPR leaves no
//  headroom — R10's 2-barrier merge spilled to scratch, +50 us.)
__global__ __launch_bounds__(512, 2)
void z_kernel(const __bf16* __restrict__ X, const __bf16* __restrict__ Gt,
              __hip_bfloat16* __restrict__ Zo)
{
  __shared__ char lds[163840];   // 2 x (A 2x16KB + B 2x24KB) = 2 x 80KB
  int f = blockIdx.x;            // 256
  f = (f & 7) * 32 + (f >> 3);   // XCD-chunked
  const int tn = f & 1, tm = f >> 1;
  const int tile_m = tm * 256, tile_n = tn * 384;

  const int tid  = threadIdx.x;
  const int lane = tid & 63;
  const int w    = tid >> 6;
  const int wm   = w >> 2, wn = w & 3;   // wave tile 128x96
  const int lrow = lane & 15;
  const int lcb  = (lane >> 4) * 16;
  const int ar   = wm * 128 + lrow;
  const int br   = wn * 96 + lrow;
  const int aB = ar * 64 + (lcb ^ (((ar >> 1) & 3) << 4));
  const int bB = br * 64 + (lcb ^ (((br >> 1) & 3) << 4));

  const int    l0 = tid * 16, l1 = l0 + 8192, l2 = l0 + 16384;
  const size_t g0 = (size_t)(l0 >> 6) * 1536 + ((l0 & 63) ^ (((l0 >> 7) & 3) << 4));
  const size_t g1 = (size_t)(l1 >> 6) * 1536 + ((l1 & 63) ^ (((l1 >> 7) & 3) << 4));
  const size_t g2 = (size_t)(l2 >> 6) * 1536 + ((l2 & 63) ^ (((l2 >> 7) & 3) << 4));

  const char* Ab = (const char*)(X + (size_t)tile_m * Cn);
  const char* Bb = (const char*)(Gt + (size_t)tile_n * Cn);

#define STAGEA(gk, du) do { const char* _g = (gk); char* _d = (du); \
    gload_lds16(_g + g0, _d + l0); gload_lds16(_g + g1, _d + l1); } while (0)
#define STAGEB(gk, du) do { const char* _g = (gk); char* _d = (du); \
    gload_lds16(_g + g0, _d + l0); gload_lds16(_g + g1, _d + l1); \
    gload_lds16(_g + g2, _d + l2); } while (0)

  f32x4 acc[8][6] = {};

  STAGEA(Ab,      lds + 0);
  STAGEB(Bb,      lds + 32768);
  STAGEA(Ab + 64, lds + 16384);
  STAGEB(Bb + 64, lds + 57344);
  asm volatile("s_waitcnt vmcnt(0)" ::: "memory");
  __builtin_amdgcn_s_barrier();

  for (int t = 0; t < KT; ++t) {
    const char* bp = lds + (t & 1) * 81920;
    char*       bq = lds + ((t + 1) & 1) * 81920;
    const char* gA = Ab + (size_t)(t + 1) * 128;
    const char* gB = Bb + (size_t)(t + 1) * 128;
    const bool st  = (t < KT - 1);
    bf16x8 aF[4], bF[6];

    // p0
#pragma unroll
    for (int i2 = 0; i2 < 6; ++i2) bF[i2] = *(const bf16x8*)(bp + 32768 + bB + i2 * 1024);
#pragma unroll
    for (int i2 = 0; i2 < 4; ++i2) aF[i2] = *(const bf16x8*)(bp + aB + i2 * 1024);
    if (st) STAGEA(gA, bq);
    __builtin_amdgcn_s_barrier();
    DS_WAIT_SB;
    __builtin_amdgcn_s_setprio(1);
#pragma unroll
    for (int i2 = 0; i2 < 4; ++i2)
#pragma unroll
      for (int j2 = 0; j2 < 6; ++j2)
        acc[i2][j2] = MFMA16x16(aF[i2], bF[j2], acc[i2][j2]);
    __builtin_amdgcn_s_setprio(0);
    __builtin_amdgcn_s_barrier();

    // p1
#pragma unroll
    for (int i2 = 0; i2 < 4; ++i2) aF[i2] = *(const bf16x8*)(bp + aB + 4096 + i2 * 1024);
    if (st) { STAGEB(gB, bq + 32768);
              asm volatile("s_waitcnt vmcnt(5)" ::: "memory"); }
    else    { asm volatile("s_waitcnt vmcnt(0)" ::: "memory"); }
    __builtin_amdgcn_s_barrier();
    DS_WAIT_SB;
    __builtin_amdgcn_s_setprio(1);
#pragma unroll
    for (int i2 = 0; i2 < 4; ++i2)
#pragma unroll
      for (int j2 = 0; j2 < 6; ++j2)
        acc[4 + i2][j2] = MFMA16x16(aF[i2], bF[j2], acc[4 + i2][j2]);
    __builtin_amdgcn_s_setprio(0);
    __builtin_amdgcn_s_barrier();

    // p2
#pragma unroll
    for (int i2 = 0; i2 < 6; ++i2) bF[i2] = *(const bf16x8*)(bp + 57344 + bB + i2 * 1024);
#pragma unroll
    for (int i2 = 0; i2 < 4; ++i2) aF[i2] = *(const bf16x8*)(bp + 16384 + aB + i2 * 1024);
    if (st) STAGEA(gA + 64, bq + 16384);
    __builtin_amdgcn_s_barrier();
    DS_WAIT_SB;
    __builtin_amdgcn_s_setprio(1);
#pragma unroll
    for (int i2 = 0; i2 < 4; ++i2)
#pragma unroll
      for (int j2 = 0; j2 < 6; ++j2)
        acc[i2][j2] = MFMA16x16(aF[i2], bF[j2], acc[i2][j2]);
    __builtin_amdgcn_s_setprio(0);
    __builtin_amdgcn_s_barrier();

    // p3
#pragma unroll
    for (int i2 = 0; i2 < 4; ++i2) aF[i2] = *(const bf16x8*)(bp + 16384 + aB + 4096 + i2 * 1024);
    if (st) { STAGEB(gB + 64, bq + 57344);
              asm volatile("s_waitcnt vmcnt(5)" ::: "memory"); }
    else    { asm volatile("s_waitcnt vmcnt(0)" ::: "memory"); }
    __builtin_amdgcn_s_barrier();
    DS_WAIT_SB;
    __builtin_amdgcn_s_setprio(1);
#pragma unroll
    for (int i2 = 0; i2 < 4; ++i2)
#pragma unroll
      for (int j2 = 0; j2 < 6; ++j2)
        acc[4 + i2][j2] = MFMA16x16(aF[i2], bF[j2], acc[4 + i2][j2]);
    __builtin_amdgcn_s_setprio(0);
    __builtin_amdgcn_s_barrier();
  }
#undef STAGEA
#undef STAGEB

  // epilogue: banded LDS repack [64][392 bf16] -> coalesced stores
  __bf16* cb = (__bf16*)lds;
  const int crow = (lane >> 4) * 4;
  for (int rb = 0; rb < 4; ++rb) {
    __syncthreads();
    if (wm == (rb >> 1)) {
#pragma unroll
      for (int mi2 = 0; mi2 < 4; ++mi2) {
        const int mi = (rb & 1) * 4 + mi2;
        const int lr = mi2 * 16 + crow;
#pragma unroll
        for (int ni = 0; ni < 6; ++ni) {
          const int col = wn * 96 + ni * 16 + lrow;
#pragma unroll
          for (int r = 0; r < 4; ++r)
            cb[(lr + r) * 392 + col] = (__bf16)acc[mi][ni][r];
        }
      }
    }
    __syncthreads();
    const int row = tid >> 3;
    const int seg = tid & 7;
    char* gout = (char*)Zo + (size_t)(tile_m + rb * 64 + row) * 1536 + tile_n * 2 + seg * 96;
    const char* lsrc = (const char*)cb + row * 784 + seg * 96;
#pragma unroll
    for (int i2 = 0; i2 < 6; ++i2)
      *(float4v*)(gout + i2 * 16) = *(const float4v*)(lsrc + i2 * 16);
  }
}

// ---------------- Gt[c'][c] = sum_d Wk[d,c']*Wq[d,c], fp32 in (transpose via LDS), bf16 out
__global__ __launch_bounds__(256)
void gt_kernel(const float* __restrict__ Wk, const float* __restrict__ Wq,
               __bf16* __restrict__ Gt)
{
  __shared__ __bf16 ak[64 * 40], bkl[64 * 40];   // [col][d], stride 40 (80B, 16B-aligned)
  const int t  = threadIdx.x;
  const int tm = (blockIdx.x / 12) * 64;   // c' tile
  const int tn = (blockIdx.x % 12) * 64;   // c  tile
  const int lane = t & 63, w = t >> 6;
  const int wm = w >> 1, wn = w & 1;       // 2x2 waves of 32x32
  const int lrow = lane & 15, lk8 = (lane >> 4) * 8, crow = (lane >> 4) * 4;
  const int lc = t & 63, ld = t >> 6;
  f32x4 acc[2][2] = {};

  for (int d0 = 0; d0 < 768; d0 += 32) {
    __syncthreads();
#pragma unroll
    for (int dd = 0; dd < 8; ++dd) {
      const int dl = ld + dd * 4;
      ak [lc * 40 + dl] = (__bf16)Wk[(size_t)(d0 + dl) * 768 + tm + lc];
      bkl[lc * 40 + dl] = (__bf16)Wq[(size_t)(d0 + dl) * 768 + tn + lc];
    }
    __syncthreads();
    bf16x8 a[2], b2[2];
#pragma unroll
    for (int mi = 0; mi < 2; ++mi)
      a[mi] = *(const bf16x8*)&ak[(wm * 32 + mi * 16 + lrow) * 40 + lk8];
#pragma unroll
    for (int ni = 0; ni < 2; ++ni)
      b2[ni] = *(const bf16x8*)&bkl[(wn * 32 + ni * 16 + lrow) * 40 + lk8];
#pragma unroll
    for (int mi = 0; mi < 2; ++mi)
#pragma unroll
      for (int ni = 0; ni < 2; ++ni)
        acc[mi][ni] = MFMA16x16(a[mi], b2[ni], acc[mi][ni]);
  }
#pragma unroll
  for (int mi = 0; mi < 2; ++mi)
#pragma unroll
    for (int ni = 0; ni < 2; ++ni)
#pragma unroll
      for (int r = 0; r < 4; ++r)
        Gt[(size_t)(tm + wm * 32 + mi * 16 + crow + r) * 768 +
           tn + wn * 32 + ni * 16 + lrow] = (__bf16)acc[mi][ni][r];
}

// ---------------- wqbk[c] = sum_d Wq[d,c]*bk[d]; wkbq[c] = sum_d Wk[d,c]*bq[d]; c0 = bq.bk
__global__ __launch_bounds__(256)
void biasprep(const float* __restrict__ Wq, const float* __restrict__ Wk,
              const float* __restrict__ bq, const float* __restrict__ bk,
              float* __restrict__ wqbk, float* __restrict__ wkbq, float* __restrict__ c0p)
{
  const int t = threadIdx.x, bx = blockIdx.x, by = blockIdx.y;
  if (by == 32) {
    if (bx == 0) {
      float s = 0.f;
#pragma unroll
      for (int i2 = 0; i2 < 3; ++i2) { const int d = t + i2 * 256; s += bq[d] * bk[d]; }
#pragma unroll
      for (int off = 32; off; off >>= 1) s += __shfl_down(s, off);
      __shared__ float rr[4];
      if ((t & 63) == 0) rr[t >> 6] = s;
      __syncthreads();
      if (t == 0) atomicAdd(c0p, rr[0] + rr[1] + rr[2] + rr[3]);
    }
    return;
  }
  const int c = bx * 256 + t;
  float aq = 0.f, ak2 = 0.f;
  for (int dd = 0; dd < 24; ++dd) {
    const int d = by * 24 + dd;
    aq  += Wq[(size_t)d * 768 + c] * bk[d];
    ak2 += Wk[(size_t)d * 768 + c] * bq[d];
  }
  atomicAdd(&wqbk[c], aq);
  atomicAdd(&wkbq[c], ak2);
}

// ---------------- cvt x->bf16 fused with u = x.wqbk + c0, v = x.wkbq
__global__ __launch_bounds__(512)
void cvt_x_uv(const float* __restrict__ x, const float* __restrict__ wqbk,
              const float* __restrict__ wkbq, const float* __restrict__ c0p,
              __hip_bfloat16* __restrict__ xb, float* __restrict__ u, float* __restrict__ v)
{
  __shared__ float wq_l[768], wk_l[768];
  const int t = threadIdx.x;
  for (int i = t; i < 768; i += 512) { wq_l[i] = wqbk[i]; wk_l[i] = wkbq[i]; }
  __syncthreads();
  const int lane = t & 63, wv = t >> 6;
  const int row = blockIdx.x * 8 + wv;
  const float4v* xr = (const float4v*)(x + (size_t)row * 768);
  short4v* xo = (short4v*)((__bf16*)xb + (size_t)row * 768);
  float du = 0.f, dv = 0.f;
#pragma unroll
  for (int i = 0; i < 3; ++i) {
    const int ch = lane + 64 * i;
    const float4v xv = xr[ch];
    short4v s;
#pragma unroll
    for (int j = 0; j < 4; ++j) {
      s[j] = __builtin_bit_cast(short, __float2bfloat16(xv[j]));
      du += xv[j] * wq_l[ch * 4 + j];
      dv += xv[j] * wk_l[ch * 4 + j];
    }
    xo[ch] = s;
  }
#pragma unroll
  for (int off = 1; off < 64; off <<= 1) {
    du += __shfl_xor(du, off);
    dv += __shfl_xor(dv, off);
  }
  if (lane == 0) { u[row] = du + *c0p; v[row] = dv; }
}

// ---------------- y[b,c] = sum_k w[b,k]*xb[b,k,c]; sw[b] = sum_k w[b,k]
// grid (16,64): 32 k-rows per block -> ~4 blocks/CU for latency hiding
__global__ __launch_bounds__(192)
void wx_kernel(const float* __restrict__ wsum, const __bf16* __restrict__ xb,
               float* __restrict__ y, float* __restrict__ swp)
{
  const int b = blockIdx.x, kc = blockIdx.y;
  const int t = threadIdx.x;
  const int chunk = t % 96, rg = t / 96;
  const __bf16* xr = xb + ((size_t)b * Tn + (size_t)kc * 32) * 768;
  const float*  wr = wsum + (size_t)b * Tn + (size_t)kc * 32;
  float acc[8] = {};
  float swl = 0.f;
  for (int k2 = 0; k2 < 16; ++k2) {
    const int k = k2 * 2 + rg;
    const float wk = wr[k];
    const bf16x8 v8 = *(const bf16x8*)&xr[(size_t)k * 768 + chunk * 8];
    if (chunk == 0) swl += wk;
#pragma unroll
    for (int j = 0; j < 8; ++j) acc[j] += wk * (float)v8[j];
  }
  float* yb = y + (size_t)b * 768 + chunk * 8;
#pragma unroll
  for (int j = 0; j < 8; ++j) atomicAdd(yb + j, acc[j]);
  if (chunk == 0) atomicAdd(&swp[b], swl);
}

// ---------------- out_pre[b,d] = ( y[b,:].Wv[d,:] + sw[b]*bv[d] ) / T
__global__ __launch_bounds__(256)
void vproj_kernel(const float* __restrict__ y, const float* __restrict__ swp,
                  const float* __restrict__ Wv, const float* __restrict__ bv,
                  float* __restrict__ opre)
{
  __shared__ float ys[768];
  const int b = blockIdx.x, dg = blockIdx.y, t = threadIdx.x;
  for (int i = t; i < 768; i += 256) ys[i] = y[(size_t)b * 768 + i];
  __syncthreads();
  const float sw = swp[b];
  const int d = dg * 256 + t;
  const float4v* wrow = (const float4v*)(Wv + (size_t)d * 768);
  const float4v* ysv  = (const float4v*)ys;
  float4v a = {};
  for (int c = 0; c < 192; ++c) {
    const float4v wv4 = wrow[c];
    const float4v yv4 = ysv[c];
#pragma unroll
    for (int j = 0; j < 4; ++j) a[j] += wv4[j] * yv4[j];
  }
  const float dot = a[0] + a[1] + a[2] + a[3];
  opre[(size_t)b * 768 + d] = (dot + sw * bv[d]) * (1.f / 2048.f);
}

// ---------------- BatchNorm1d over batch dim
__global__ void bn_kernel(const float* __restrict__ out_pre,
                          const float* __restrict__ gamma, const float* __restrict__ beta,
                          float* __restrict__ out)
{
  const int d = blockIdx.x * 256 + threadIdx.x;
  float vals[16];
  float s = 0.f;
#pragma unroll
  for (int b = 0; b < 16; ++b) { vals[b] = out_pre[b * Cn + d]; s += vals[b]; }
  const float mu = s * (1.f / 16.f);
  float s2 = 0.f;
#pragma unroll
  for (int b = 0; b < 16; ++b) { float t2 = vals[b] - mu; s2 += t2 * t2; }
  const float inv = rsqrtf(s2 * (1.f / 16.f) + 1e-5f);
  const float g = gamma[d] * inv, be = beta[d];
#pragma unroll
  for (int b = 0; b < 16; ++b) out[b * Cn + d] = (vals[b] - mu) * g + be;
}

extern "C" void kernel_launch(void* const* d_in, const int* in_sizes, int n_in,
                              void* d_out, int out_size, void* d_ws, size_t ws_size,
                              hipStream_t stream)
{
  const float* x  = (const float*)d_in[0];
  const float* Wq = (const float*)d_in[1];
  const float* bq = (const float*)d_in[2];
  const float* Wk = (const float*)d_in[3];
  const float* bk = (const float*)d_in[4];
  const float* Wv = (const float*)d_in[5];
  const float* bv = (const float*)d_in[6];
  const float* gamma = (const float*)d_in[7];
  const float* beta  = (const float*)d_in[8];
  float* out = (float*)d_out;

  char* ws = (char*)d_ws;
  // workspace layout (~97.6 MiB)
  __hip_bfloat16* xb  = (__hip_bfloat16*)(ws);                  // 50,331,648
  __hip_bfloat16* Zb  = (__hip_bfloat16*)(ws + 50331648);       // 50,331,648
  __bf16*         Gt  = (__bf16*)        (ws + 100663296);      //  1,179,648
  float*          u   = (float*)         (ws + 101842944);      //    131,072
  float*          v   = (float*)         (ws + 101974016);      //    131,072
  float*          wsum= (float*)         (ws + 102105088);      //    131,072  <- zero from here
  float*          yv  = (float*)         (ws + 102236160);      //     49,152
  float*          wqbk= (float*)         (ws + 102285312);      //      3,072
  float*          wkbq= (float*)         (ws + 102288384);      //      3,072
  float*          c0p = (float*)         (ws + 102291456);      //         64
  float*          swp = (float*)         (ws + 102291520);      //         64
  float*          opre= (float*)         (ws + 102291584);      //     49,152

  (void)in_sizes; (void)n_in; (void)out_size; (void)ws_size;

  // zero wsum + yv + wqbk + wkbq + c0 + sw (contiguous; atomics accumulate into these)
  hipMemsetAsync(wsum, 0, 131072 + 49152 + 3072 + 3072 + 64 + 64, stream);

  biasprep<<<dim3(3, 33), 256, 0, stream>>>(Wq, Wk, bq, bk, wqbk, wkbq, c0p);
  gt_kernel<<<dim3(144), 256, 0, stream>>>(Wk, Wq, Gt);
  cvt_x_uv<<<dim3(4096), 512, 0, stream>>>(x, wqbk, wkbq, c0p, xb, u, v);

  z_kernel<<<dim3(256), 512, 0, stream>>>((const __bf16*)xb, Gt, Zb);

  attn_kernel<<<dim3(256), 512, 0, stream>>>(
      (const __bf16*)Zb, (const __bf16*)xb, u, v, wsum);

  wx_kernel<<<dim3(16, 64), 192, 0, stream>>>(wsum, (const __bf16*)xb, yv, swp);
  vproj_kernel<<<dim3(16, 3), 256, 0, stream>>>(yv, swp, Wv, bv, opre);
  bn_kernel<<<dim3(3), 256, 0, stream>>>(opre, gamma, beta, out);
}

// Round 12
// 253.865 us; speedup vs baseline: 1.2343x; 1.1653x over previous
//
#include <hip/hip_runtime.h>
#include <hip/hip_bf16.h>

typedef __bf16 bf16x8 __attribute__((ext_vector_type(8)));
typedef float  f32x4  __attribute__((ext_vector_type(4)));
typedef float  float4v __attribute__((ext_vector_type(4)));
typedef short  short4v __attribute__((ext_vector_type(4)));

static constexpr int Tn  = 2048;
static constexpr int Bn  = 16;
static constexpr int Cn  = 768;
static constexpr int KT  = 12;       // 768 / 64 K-steps

#define MFMA16x16(a, b, c) __builtin_amdgcn_mfma_f32_16x16x32_bf16(a, b, c, 0, 0, 0)
#define DS_WAIT    asm volatile("s_waitcnt lgkmcnt(0)" ::: "memory")
#define DS_WAIT_SB do { asm volatile("s_waitcnt lgkmcnt(0)" ::: "memory"); \
                        __builtin_amdgcn_sched_barrier(0); } while (0)

__device__ __forceinline__ void gload_lds16(const void* g, void* l) {
  __builtin_amdgcn_global_load_lds((const __attribute__((address_space(1))) void*)g,
                                   (__attribute__((address_space(3))) void*)l, 16, 0, 0);
}

// ---------------- persistent attention colsum, 2-phase K-step (R9, measured ~104-105 us):
__global__ __launch_bounds__(512, 2)
void attn_kernel(const __bf16* __restrict__ Z, const __bf16* __restrict__ X,
                 const float* __restrict__ u, const float* __restrict__ v,
                 float* __restrict__ wsum)
{
  __shared__ char lds[131072];
  const int i   = blockIdx.x;          // 256
  const int xcd = i & 7, j = i >> 3;   // j 0..31
  const int b    = xcd * 2 + (j >> 4);
  const int qt   = (j >> 1) & 7;
  const int half = j & 1;              // kt in {half*4 .. half*4+3}

  const int tid  = threadIdx.x;
  const int lane = tid & 63;
  const int w    = tid >> 6;
  const int wm   = w >> 2, wn = w & 3;
  const int lrow = lane & 15;
  const int lcb  = (lane >> 4) * 16;
  const int ar   = wm * 128 + lrow;
  const int br   = wn * 64 + lrow;
  const int crow = (lane >> 4) * 4;

  const int aB = ar * 64 + (lcb ^ (((ar >> 1) & 3) << 4));
  const int bB = br * 64 + (lcb ^ (((br >> 1) & 3) << 4));

  const int    l0 = tid * 16,            l1 = tid * 16 + 8192;
  const size_t g0 = (size_t)(l0 >> 6) * 1536 + ((l0 & 63) ^ (((l0 >> 7) & 3) << 4));
  const size_t g1 = (size_t)(l1 >> 6) * 1536 + ((l1 & 63) ^ (((l1 >> 7) & 3) << 4));

  const char* Ab  = (const char*)(Z + ((size_t)b * Tn + qt * 256) * Cn);
  const char* Xb0 = (const char*)(X + ((size_t)b * Tn + (size_t)(half * 4) * 256) * Cn);

#define STAGE(gk, du) do { const char* _g = (gk); char* _d = (du); \
    gload_lds16(_g + g0, _d + l0); gload_lds16(_g + g1, _d + l1); } while (0)

  STAGE(Ab,       lds + 0);
  STAGE(Xb0,      lds + 32768);
  STAGE(Ab + 64,  lds + 16384);
  STAGE(Xb0 + 64, lds + 49152);
  asm volatile("s_waitcnt vmcnt(0)" ::: "memory");
  __builtin_amdgcn_s_barrier();

  const float kf = 0.036084391824351615f * 1.4426950408889634f;  // scale * log2(e)
  int cur = 0;

#pragma unroll 1
  for (int tt = 0; tt < 4; ++tt) {
    const int kt = half * 4 + tt;
    f32x4 acc[8][4] = {};

    for (int t = 0; t < KT; ++t) {
      const char* bp = lds + cur * 65536;
      char*       bq = lds + (cur ^ 1) * 65536;
      const bool last = (t == KT - 1);
      const bool st   = !(tt == 3 && last);
      const size_t koff = last ? 0 : (size_t)(t + 1) * 128;
      const char* gA = Ab + koff;
      const char* gB = Xb0 + (size_t)(tt + (last ? 1 : 0)) * 393216 + koff;
      bf16x8 aF[8], bF[4];

      // ---- phase ks0
#pragma unroll
      for (int i2 = 0; i2 < 4; ++i2) bF[i2] = *(const bf16x8*)(bp + 32768 + bB + i2 * 1024);
#pragma unroll
      for (int i2 = 0; i2 < 4; ++i2) aF[i2]     = *(const bf16x8*)(bp + aB + i2 * 1024);
#pragma unroll
      for (int i2 = 0; i2 < 4; ++i2) aF[4 + i2] = *(const bf16x8*)(bp + aB + 4096 + i2 * 1024);
      if (st) { STAGE(gA, bq); STAGE(gB, bq + 32768); }
      DS_WAIT;
      __builtin_amdgcn_s_setprio(1);
#pragma unroll
      for (int i2 = 0; i2 < 8; ++i2)
#pragma unroll
        for (int j2 = 0; j2 < 4; ++j2)
          acc[i2][j2] = MFMA16x16(aF[i2], bF[j2], acc[i2][j2]);
      __builtin_amdgcn_s_setprio(0);
      if (st) { asm volatile("s_waitcnt vmcnt(4)" ::: "memory"); }
      else    { asm volatile("s_waitcnt vmcnt(0)" ::: "memory"); }
      __builtin_amdgcn_s_barrier();

      // ---- phase ks1
#pragma unroll
      for (int i2 = 0; i2 < 4; ++i2) bF[i2] = *(const bf16x8*)(bp + 49152 + bB + i2 * 1024);
#pragma unroll
      for (int i2 = 0; i2 < 4; ++i2) aF[i2]     = *(const bf16x8*)(bp + 16384 + aB + i2 * 1024);
#pragma unroll
      for (int i2 = 0; i2 < 4; ++i2) aF[4 + i2] = *(const bf16x8*)(bp + 16384 + aB + 4096 + i2 * 1024);
      if (st) { STAGE(gA + 64, bq + 16384); STAGE(gB + 64, bq + 49152); }
      DS_WAIT;
      __builtin_amdgcn_s_setprio(1);
#pragma unroll
      for (int i2 = 0; i2 < 8; ++i2)
#pragma unroll
        for (int j2 = 0; j2 < 4; ++j2)
          acc[i2][j2] = MFMA16x16(aF[i2], bF[j2], acc[i2][j2]);
      __builtin_amdgcn_s_setprio(0);
      if (st) { asm volatile("s_waitcnt vmcnt(4)" ::: "memory"); }
      else    { asm volatile("s_waitcnt vmcnt(0)" ::: "memory"); }
      __builtin_amdgcn_s_barrier();
      cur ^= 1;
    }

    // per-tile epilogue: sigmoid + column-sum + atomics (no LDS use)
    float vv[4];
#pragma unroll
    for (int ni = 0; ni < 4; ++ni)
      vv[ni] = v[(size_t)b * Tn + kt * 256 + wn * 64 + ni * 16 + lrow];

    float csum[4] = {0.f, 0.f, 0.f, 0.f};
#pragma unroll
    for (int mi = 0; mi < 8; ++mi) {
      const f32x4 uu = *(const f32x4*)&u[(size_t)b * Tn + qt * 256 + wm * 128 +
                                         (mi >> 2) * 64 + (mi & 3) * 16 + crow];
#pragma unroll
      for (int ni = 0; ni < 4; ++ni)
#pragma unroll
        for (int rr = 0; rr < 4; ++rr) {
          const float e = __builtin_amdgcn_exp2f(-(acc[mi][ni][rr] + uu[rr] + vv[ni]) * kf);
          csum[ni] += __builtin_amdgcn_rcpf(1.f + e);
        }
    }
#pragma unroll
    for (int ni = 0; ni < 4; ++ni) {
      csum[ni] += __shfl_xor(csum[ni], 16);
      csum[ni] += __shfl_xor(csum[ni], 32);
    }
    if (lane < 16) {
#pragma unroll
      for (int ni = 0; ni < 4; ++ni)
        atomicAdd(&wsum[(size_t)b * Tn + kt * 256 + wn * 64 + ni * 16 + lane], csum[ni]);
    }
  }
#undef STAGE
}

// ---------------- Z = X * Gt^T: 256x384 tiles, 256 blocks, one round
// (EXACT R8/R9 measured form: 4-phase, hoisted STAGEA/STAGEB, sched_barrier'd DS_WAIT.
//  DO NOT merge phases or drop the sched_barrier: acc[8][6]=192 VGPR leaves no
//  headroom — R10's 2-barrier merge spilled to scratch, +50 us.)
__global__ __launch_bounds__(512, 2)
void z_kernel(const __bf16* __restrict__ X, const __bf16* __restrict__ Gt,
              __hip_bfloat16* __restrict__ Zo)
{
  __shared__ char lds[163840];   // 2 x (A 2x16KB + B 2x24KB) = 2 x 80KB
  int f = blockIdx.x;            // 256
  f = (f & 7) * 32 + (f >> 3);   // XCD-chunked
  const int tn = f & 1, tm = f >> 1;
  const int tile_m = tm * 256, tile_n = tn * 384;

  const int tid  = threadIdx.x;
  const int lane = tid & 63;
  const int w    = tid >> 6;
  const int wm   = w >> 2, wn = w & 3;   // wave tile 128x96
  const int lrow = lane & 15;
  const int lcb  = (lane >> 4) * 16;
  const int ar   = wm * 128 + lrow;
  const int br   = wn * 96 + lrow;
  const int aB = ar * 64 + (lcb ^ (((ar >> 1) & 3) << 4));
  const int bB = br * 64 + (lcb ^ (((br >> 1) & 3) << 4));

  const int    l0 = tid * 16, l1 = l0 + 8192, l2 = l0 + 16384;
  const size_t g0 = (size_t)(l0 >> 6) * 1536 + ((l0 & 63) ^ (((l0 >> 7) & 3) << 4));
  const size_t g1 = (size_t)(l1 >> 6) * 1536 + ((l1 & 63) ^ (((l1 >> 7) & 3) << 4));
  const size_t g2 = (size_t)(l2 >> 6) * 1536 + ((l2 & 63) ^ (((l2 >> 7) & 3) << 4));

  const char* Ab = (const char*)(X + (size_t)tile_m * Cn);
  const char* Bb = (const char*)(Gt + (size_t)tile_n * Cn);

#define STAGEA(gk, du) do { const char* _g = (gk); char* _d = (du); \
    gload_lds16(_g + g0, _d + l0); gload_lds16(_g + g1, _d + l1); } while (0)
#define STAGEB(gk, du) do { const char* _g = (gk); char* _d = (du); \
    gload_lds16(_g + g0, _d + l0); gload_lds16(_g + g1, _d + l1); \
    gload_lds16(_g + g2, _d + l2); } while (0)

  f32x4 acc[8][6] = {};

  STAGEA(Ab,      lds + 0);
  STAGEB(Bb,      lds + 32768);
  STAGEA(Ab + 64, lds + 16384);
  STAGEB(Bb + 64, lds + 57344);
  asm volatile("s_waitcnt vmcnt(0)" ::: "memory");
  __builtin_amdgcn_s_barrier();

  for (int t = 0; t < KT; ++t) {
    const char* bp = lds + (t & 1) * 81920;
    char*       bq = lds + ((t + 1) & 1) * 81920;
    const char* gA = Ab + (size_t)(t + 1) * 128;
    const char* gB = Bb + (size_t)(t + 1) * 128;
    const bool st  = (t < KT - 1);
    bf16x8 aF[4], bF[6];

    // p0
#pragma unroll
    for (int i2 = 0; i2 < 6; ++i2) bF[i2] = *(const bf16x8*)(bp + 32768 + bB + i2 * 1024);
#pragma unroll
    for (int i2 = 0; i2 < 4; ++i2) aF[i2] = *(const bf16x8*)(bp + aB + i2 * 1024);
    if (st) STAGEA(gA, bq);
    __builtin_amdgcn_s_barrier();
    DS_WAIT_SB;
    __builtin_amdgcn_s_setprio(1);
#pragma unroll
    for (int i2 = 0; i2 < 4; ++i2)
#pragma unroll
      for (int j2 = 0; j2 < 6; ++j2)
        acc[i2][j2] = MFMA16x16(aF[i2], bF[j2], acc[i2][j2]);
    __builtin_amdgcn_s_setprio(0);
    __builtin_amdgcn_s_barrier();

    // p1
#pragma unroll
    for (int i2 = 0; i2 < 4; ++i2) aF[i2] = *(const bf16x8*)(bp + aB + 4096 + i2 * 1024);
    if (st) { STAGEB(gB, bq + 32768);
              asm volatile("s_waitcnt vmcnt(5)" ::: "memory"); }
    else    { asm volatile("s_waitcnt vmcnt(0)" ::: "memory"); }
    __builtin_amdgcn_s_barrier();
    DS_WAIT_SB;
    __builtin_amdgcn_s_setprio(1);
#pragma unroll
    for (int i2 = 0; i2 < 4; ++i2)
#pragma unroll
      for (int j2 = 0; j2 < 6; ++j2)
        acc[4 + i2][j2] = MFMA16x16(aF[i2], bF[j2], acc[4 + i2][j2]);
    __builtin_amdgcn_s_setprio(0);
    __builtin_amdgcn_s_barrier();

    // p2
#pragma unroll
    for (int i2 = 0; i2 < 6; ++i2) bF[i2] = *(const bf16x8*)(bp + 57344 + bB + i2 * 1024);
#pragma unroll
    for (int i2 = 0; i2 < 4; ++i2) aF[i2] = *(const bf16x8*)(bp + 16384 + aB + i2 * 1024);
    if (st) STAGEA(gA + 64, bq + 16384);
    __builtin_amdgcn_s_barrier();
    DS_WAIT_SB;
    __builtin_amdgcn_s_setprio(1);
#pragma unroll
    for (int i2 = 0; i2 < 4; ++i2)
#pragma unroll
      for (int j2 = 0; j2 < 6; ++j2)
        acc[i2][j2] = MFMA16x16(aF[i2], bF[j2], acc[i2][j2]);
    __builtin_amdgcn_s_setprio(0);
    __builtin_amdgcn_s_barrier();

    // p3
#pragma unroll
    for (int i2 = 0; i2 < 4; ++i2) aF[i2] = *(const bf16x8*)(bp + 16384 + aB + 4096 + i2 * 1024);
    if (st) { STAGEB(gB + 64, bq + 57344);
              asm volatile("s_waitcnt vmcnt(5)" ::: "memory"); }
    else    { asm volatile("s_waitcnt vmcnt(0)" ::: "memory"); }
    __builtin_amdgcn_s_barrier();
    DS_WAIT_SB;
    __builtin_amdgcn_s_setprio(1);
#pragma unroll
    for (int i2 = 0; i2 < 4; ++i2)
#pragma unroll
      for (int j2 = 0; j2 < 6; ++j2)
        acc[4 + i2][j2] = MFMA16x16(aF[i2], bF[j2], acc[4 + i2][j2]);
    __builtin_amdgcn_s_setprio(0);
    __builtin_amdgcn_s_barrier();
  }
#undef STAGEA
#undef STAGEB

  // epilogue: banded LDS repack [64][392 bf16] -> coalesced stores
  __bf16* cb = (__bf16*)lds;
  const int crow = (lane >> 4) * 4;
  for (int rb = 0; rb < 4; ++rb) {
    __syncthreads();
    if (wm == (rb >> 1)) {
#pragma unroll
      for (int mi2 = 0; mi2 < 4; ++mi2) {
        const int mi = (rb & 1) * 4 + mi2;
        const int lr = mi2 * 16 + crow;
#pragma unroll
        for (int ni = 0; ni < 6; ++ni) {
          const int col = wn * 96 + ni * 16 + lrow;
#pragma unroll
          for (int r = 0; r < 4; ++r)
            cb[(lr + r) * 392 + col] = (__bf16)acc[mi][ni][r];
        }
      }
    }
    __syncthreads();
    const int row = tid >> 3;
    const int seg = tid & 7;
    char* gout = (char*)Zo + (size_t)(tile_m + rb * 64 + row) * 1536 + tile_n * 2 + seg * 96;
    const char* lsrc = (const char*)cb + row * 784 + seg * 96;
#pragma unroll
    for (int i2 = 0; i2 < 6; ++i2)
      *(float4v*)(gout + i2 * 16) = *(const float4v*)(lsrc + i2 * 16);
  }
}

// ---------------- Gt[c'][c] = sum_d Wk[d,c']*Wq[d,c], fp32 in (transpose via LDS), bf16 out
__global__ __launch_bounds__(256)
void gt_kernel(const float* __restrict__ Wk, const float* __restrict__ Wq,
               __bf16* __restrict__ Gt)
{
  __shared__ __bf16 ak[64 * 40], bkl[64 * 40];   // [col][d], stride 40 (80B, 16B-aligned)
  const int t  = threadIdx.x;
  const int tm = (blockIdx.x / 12) * 64;   // c' tile
  const int tn = (blockIdx.x % 12) * 64;   // c  tile
  const int lane = t & 63, w = t >> 6;
  const int wm = w >> 1, wn = w & 1;       // 2x2 waves of 32x32
  const int lrow = lane & 15, lk8 = (lane >> 4) * 8, crow = (lane >> 4) * 4;
  const int lc = t & 63, ld = t >> 6;
  f32x4 acc[2][2] = {};

  for (int d0 = 0; d0 < 768; d0 += 32) {
    __syncthreads();
#pragma unroll
    for (int dd = 0; dd < 8; ++dd) {
      const int dl = ld + dd * 4;
      ak [lc * 40 + dl] = (__bf16)Wk[(size_t)(d0 + dl) * 768 + tm + lc];
      bkl[lc * 40 + dl] = (__bf16)Wq[(size_t)(d0 + dl) * 768 + tn + lc];
    }
    __syncthreads();
    bf16x8 a[2], b2[2];
#pragma unroll
    for (int mi = 0; mi < 2; ++mi)
      a[mi] = *(const bf16x8*)&ak[(wm * 32 + mi * 16 + lrow) * 40 + lk8];
#pragma unroll
    for (int ni = 0; ni < 2; ++ni)
      b2[ni] = *(const bf16x8*)&bkl[(wn * 32 + ni * 16 + lrow) * 40 + lk8];
#pragma unroll
    for (int mi = 0; mi < 2; ++mi)
#pragma unroll
      for (int ni = 0; ni < 2; ++ni)
        acc[mi][ni] = MFMA16x16(a[mi], b2[ni], acc[mi][ni]);
  }
#pragma unroll
  for (int mi = 0; mi < 2; ++mi)
#pragma unroll
    for (int ni = 0; ni < 2; ++ni)
#pragma unroll
      for (int r = 0; r < 4; ++r)
        Gt[(size_t)(tm + wm * 32 + mi * 16 + crow + r) * 768 +
           tn + wn * 32 + ni * 16 + lrow] = (__bf16)acc[mi][ni][r];
}

// ---------------- wqbk[c] = sum_d Wq[d,c]*bk[d]; wkbq[c] = sum_d Wk[d,c]*bq[d]; c0 = bq.bk
__global__ __launch_bounds__(256)
void biasprep(const float* __restrict__ Wq, const float* __restrict__ Wk,
              const float* __restrict__ bq, const float* __restrict__ bk,
              float* __restrict__ wqbk, float* __restrict__ wkbq, float* __restrict__ c0p)
{
  const int t = threadIdx.x, bx = blockIdx.x, by = blockIdx.y;
  if (by == 32) {
    if (bx == 0) {
      float s = 0.f;
#pragma unroll
      for (int i2 = 0; i2 < 3; ++i2) { const int d = t + i2 * 256; s += bq[d] * bk[d]; }
#pragma unroll
      for (int off = 32; off; off >>= 1) s += __shfl_down(s, off);
      __shared__ float rr[4];
      if ((t & 63) == 0) rr[t >> 6] = s;
      __syncthreads();
      if (t == 0) atomicAdd(c0p, rr[0] + rr[1] + rr[2] + rr[3]);
    }
    return;
  }
  const int c = bx * 256 + t;
  float aq = 0.f, ak2 = 0.f;
  for (int dd = 0; dd < 24; ++dd) {
    const int d = by * 24 + dd;
    aq  += Wq[(size_t)d * 768 + c] * bk[d];
    ak2 += Wk[(size_t)d * 768 + c] * bq[d];
  }
  atomicAdd(&wqbk[c], aq);
  atomicAdd(&wkbq[c], ak2);
}

// ---------------- cvt x->bf16 fused with u = x.wqbk + c0, v = x.wkbq
__global__ __launch_bounds__(512)
void cvt_x_uv(const float* __restrict__ x, const float* __restrict__ wqbk,
              const float* __restrict__ wkbq, const float* __restrict__ c0p,
              __hip_bfloat16* __restrict__ xb, float* __restrict__ u, float* __restrict__ v)
{
  __shared__ float wq_l[768], wk_l[768];
  const int t = threadIdx.x;
  for (int i = t; i < 768; i += 512) { wq_l[i] = wqbk[i]; wk_l[i] = wkbq[i]; }
  __syncthreads();
  const int lane = t & 63, wv = t >> 6;
  const int row = blockIdx.x * 8 + wv;
  const float4v* xr = (const float4v*)(x + (size_t)row * 768);
  short4v* xo = (short4v*)((__bf16*)xb + (size_t)row * 768);
  float du = 0.f, dv = 0.f;
#pragma unroll
  for (int i = 0; i < 3; ++i) {
    const int ch = lane + 64 * i;
    const float4v xv = xr[ch];
    short4v s;
#pragma unroll
    for (int j = 0; j < 4; ++j) {
      s[j] = __builtin_bit_cast(short, __float2bfloat16(xv[j]));
      du += xv[j] * wq_l[ch * 4 + j];
      dv += xv[j] * wk_l[ch * 4 + j];
    }
    xo[ch] = s;
  }
#pragma unroll
  for (int off = 1; off < 64; off <<= 1) {
    du += __shfl_xor(du, off);
    dv += __shfl_xor(dv, off);
  }
  if (lane == 0) { u[row] = du + *c0p; v[row] = dv; }
}

// ---------------- y[b,c] = sum_k w[b,k]*xb[b,k,c]; sw[b] = sum_k w[b,k]
// grid (16,16), 128 k-rows per block — R9-measured form; (16,64) costs +40 us
// from 4x atomic contention on y[b,:].
__global__ __launch_bounds__(192)
void wx_kernel(const float* __restrict__ wsum, const __bf16* __restrict__ xb,
               float* __restrict__ y, float* __restrict__ swp)
{
  const int b = blockIdx.x, kc = blockIdx.y;   // (16,16): 128 k-rows each
  const int t = threadIdx.x;
  const int chunk = t % 96, rg = t / 96;
  const __bf16* xr = xb + ((size_t)b * Tn + (size_t)kc * 128) * 768;
  const float*  wr = wsum + (size_t)b * Tn + (size_t)kc * 128;
  float acc[8] = {};
  float swl = 0.f;
  for (int k2 = 0; k2 < 64; ++k2) {
    const int k = k2 * 2 + rg;
    const float wk = wr[k];
    const bf16x8 v8 = *(const bf16x8*)&xr[(size_t)k * 768 + chunk * 8];
    if (chunk == 0) swl += wk;
#pragma unroll
    for (int j = 0; j < 8; ++j) acc[j] += wk * (float)v8[j];
  }
  float* yb = y + (size_t)b * 768 + chunk * 8;
#pragma unroll
  for (int j = 0; j < 8; ++j) atomicAdd(yb + j, acc[j]);
  if (chunk == 0) atomicAdd(&swp[b], swl);
}

// ---------------- out_pre[b,d] = ( y[b,:].Wv[d,:] + sw[b]*bv[d] ) / T
__global__ __launch_bounds__(256)
void vproj_kernel(const float* __restrict__ y, const float* __restrict__ swp,
                  const float* __restrict__ Wv, const float* __restrict__ bv,
                  float* __restrict__ opre)
{
  __shared__ float ys[768];
  const int b = blockIdx.x, dg = blockIdx.y, t = threadIdx.x;
  for (int i = t; i < 768; i += 256) ys[i] = y[(size_t)b * 768 + i];
  __syncthreads();
  const float sw = swp[b];
  const int d = dg * 256 + t;
  const float4v* wrow = (const float4v*)(Wv + (size_t)d * 768);
  const float4v* ysv  = (const float4v*)ys;
  float4v a = {};
  for (int c = 0; c < 192; ++c) {
    const float4v wv4 = wrow[c];
    const float4v yv4 = ysv[c];
#pragma unroll
    for (int j = 0; j < 4; ++j) a[j] += wv4[j] * yv4[j];
  }
  const float dot = a[0] + a[1] + a[2] + a[3];
  opre[(size_t)b * 768 + d] = (dot + sw * bv[d]) * (1.f / 2048.f);
}

// ---------------- BatchNorm1d over batch dim
__global__ void bn_kernel(const float* __restrict__ out_pre,
                          const float* __restrict__ gamma, const float* __restrict__ beta,
                          float* __restrict__ out)
{
  const int d = blockIdx.x * 256 + threadIdx.x;
  float vals[16];
  float s = 0.f;
#pragma unroll
  for (int b = 0; b < 16; ++b) { vals[b] = out_pre[b * Cn + d]; s += vals[b]; }
  const float mu = s * (1.f / 16.f);
  float s2 = 0.f;
#pragma unroll
  for (int b = 0; b < 16; ++b) { float t2 = vals[b] - mu; s2 += t2 * t2; }
  const float inv = rsqrtf(s2 * (1.f / 16.f) + 1e-5f);
  const float g = gamma[d] * inv, be = beta[d];
#pragma unroll
  for (int b = 0; b < 16; ++b) out[b * Cn + d] = (vals[b] - mu) * g + be;
}

extern "C" void kernel_launch(void* const* d_in, const int* in_sizes, int n_in,
                              void* d_out, int out_size, void* d_ws, size_t ws_size,
                              hipStream_t stream)
{
  const float* x  = (const float*)d_in[0];
  const float* Wq = (const float*)d_in[1];
  const float* bq = (const float*)d_in[2];
  const float* Wk = (const float*)d_in[3];
  const float* bk = (const float*)d_in[4];
  const float* Wv = (const float*)d_in[5];
  const float* bv = (const float*)d_in[6];
  const float* gamma = (const float*)d_in[7];
  const float* beta  = (const float*)d_in[8];
  float* out = (float*)d_out;

  char* ws = (char*)d_ws;
  // workspace layout (~97.6 MiB)
  __hip_bfloat16* xb  = (__hip_bfloat16*)(ws);                  // 50,331,648
  __hip_bfloat16* Zb  = (__hip_bfloat16*)(ws + 50331648);       // 50,331,648
  __bf16*         Gt  = (__bf16*)        (ws + 100663296);      //  1,179,648
  float*          u   = (float*)         (ws + 101842944);      //    131,072
  float*          v   = (float*)         (ws + 101974016);      //    131,072
  float*          wsum= (float*)         (ws + 102105088);      //    131,072  <- zero from here
  float*          yv  = (float*)         (ws + 102236160);      //     49,152
  float*          wqbk= (float*)         (ws + 102285312);      //      3,072
  float*          wkbq= (float*)         (ws + 102288384);      //      3,072
  float*          c0p = (float*)         (ws + 102291456);      //         64
  float*          swp = (float*)         (ws + 102291520);      //         64
  float*          opre= (float*)         (ws + 102291584);      //     49,152

  (void)in_sizes; (void)n_in; (void)out_size; (void)ws_size;

  // zero wsum + yv + wqbk + wkbq + c0 + sw (contiguous; atomics accumulate into these)
  hipMemsetAsync(wsum, 0, 131072 + 49152 + 3072 + 3072 + 64 + 64, stream);

  biasprep<<<dim3(3, 33), 256, 0, stream>>>(Wq, Wk, bq, bk, wqbk, wkbq, c0p);
  gt_kernel<<<dim3(144), 256, 0, stream>>>(Wk, Wq, Gt);
  cvt_x_uv<<<dim3(4096), 512, 0, stream>>>(x, wqbk, wkbq, c0p, xb, u, v);

  z_kernel<<<dim3(256), 512, 0, stream>>>((const __bf16*)xb, Gt, Zb);

  attn_kernel<<<dim3(256), 512, 0, stream>>>(
      (const __bf16*)Zb, (const __bf16*)xb, u, v, wsum);

  wx_kernel<<<dim3(16, 16), 192, 0, stream>>>(wsum, (const __bf16*)xb, yv, swp);
  vproj_kernel<<<dim3(16, 3), 256, 0, stream>>>(yv, swp, Wv, bv, opre);
  bn_kernel<<<dim3(3), 256, 0, stream>>>(opre, gamma, beta, out);
}